// Round 13
// baseline (323.309 us; speedup 1.0000x reference)
//
#include <hip/hip_runtime.h>
#include <math.h>

typedef unsigned short u16;
typedef __bf16  bf16x8 __attribute__((ext_vector_type(8)));
typedef float   f32x4  __attribute__((ext_vector_type(4)));
typedef unsigned short u16x8 __attribute__((ext_vector_type(8)));

#define SEQ 1024
#define MR  4096          // BATCH*SEQ rows
#define DIP 2192          // in_proj output width
#define DI  1024          // d_inner
#define NH  16
#define CD  1152          // conv dim
#define NCH 32            // chunks per sequence
#define CT  32            // timesteps per chunk
#define NIN (DIP*512)
#define NOUT (512*1024)
// ygh/ygl live in the dead xBC tail of Z rows: row stride 4384 u16,
// hi plane at +2048, lo plane at +3072 (u16 units)
#define ZROW 4384

__device__ __forceinline__ u16 f2bf(float f) {
  union { float f; unsigned u; } v; v.f = f;
  unsigned r = v.u + 0x7FFFu + ((v.u >> 16) & 1u);
  return (u16)(r >> 16);
}
__device__ __forceinline__ float bf2f(u16 h) {
  union { unsigned u; float f; } v; v.u = ((unsigned)h) << 16; return v.f;
}
__device__ __forceinline__ void splitbf(float v, u16& h, u16& l) {
  h = f2bf(v); l = f2bf(v - bf2f(h));
}
__device__ __forceinline__ float sigm(float x){ return 1.f/(1.f+__expf(-x)); }

// pack split-bf16 pair into one u32: hi in [15:0], lo in [31:16]
__device__ __forceinline__ unsigned packbf(float v) {
  u16 hh, ll; splitbf(v, hh, ll);
  return (unsigned)hh | ((unsigned)ll << 16);
}
__device__ __forceinline__ float unpackf(unsigned w) {
  return bf2f((u16)w) + bf2f((u16)(w >> 16));
}

// unpack 8 contiguous packed u32 -> hi/lo bf16x8 fragments
__device__ __forceinline__ void unpack8(const unsigned* p, bf16x8& H, bf16x8& L) {
  uint4 a = *(const uint4*)p, b = *(const uint4*)(p+4);
  u16x8 hu, lu;
  hu[0]=(u16)a.x; lu[0]=(u16)(a.x>>16);
  hu[1]=(u16)a.y; lu[1]=(u16)(a.y>>16);
  hu[2]=(u16)a.z; lu[2]=(u16)(a.z>>16);
  hu[3]=(u16)a.w; lu[3]=(u16)(a.w>>16);
  hu[4]=(u16)b.x; lu[4]=(u16)(b.x>>16);
  hu[5]=(u16)b.y; lu[5]=(u16)(b.y>>16);
  hu[6]=(u16)b.z; lu[6]=(u16)(b.z>>16);
  hu[7]=(u16)b.w; lu[7]=(u16)(b.w>>16);
  H = __builtin_bit_cast(bf16x8, hu);
  L = __builtin_bit_cast(bf16x8, lu);
}
// unpack 8 strided packed u32 -> hi/lo bf16x8
__device__ __forceinline__ void unpack8s(const unsigned* p, int stride, bf16x8& H, bf16x8& L) {
  u16x8 hu, lu;
  #pragma unroll
  for (int jj=0;jj<8;jj++){ unsigned w = p[(size_t)jj*stride]; hu[jj]=(u16)w; lu[jj]=(u16)(w>>16); }
  H = __builtin_bit_cast(bf16x8, hu);
  L = __builtin_bit_cast(bf16x8, lu);
}

// async global->LDS, 16B per lane
__device__ __forceinline__ void gl16(const u16* g, u16* l) {
  __builtin_amdgcn_global_load_lds((const __attribute__((address_space(1))) void*)g,
                                   (__attribute__((address_space(3))) void*)l,
                                   16, 0, 0);
}

// ---------------- K0: fused prep = rmsnorm(x) + weight cast + out seed ----------------
__global__ __launch_bounds__(256) void prep(
  const float* __restrict__ x, const float* __restrict__ norm_w,
  const float* __restrict__ f_in, const float* __restrict__ b_in,
  const float* __restrict__ f_out, const float* __restrict__ b_out,
  const float* __restrict__ proj,
  u16* __restrict__ H, u16* __restrict__ L, unsigned* __restrict__ wpk,
  u16* __restrict__ hbh, u16* __restrict__ hbl, float* __restrict__ out)
{
  constexpr int TOT = 2*NIN + 3*NOUT;
  constexpr int WBLK = (TOT + 255)/256;
  int blk = blockIdx.x, tid = threadIdx.x;
  if (blk < MR) {
    int m = blk;
    const float* xr = x + (size_t)m*512;
    float2 v = *(const float2*)&xr[tid*2];
    float ss = v.x*v.x + v.y*v.y;
    #pragma unroll
    for (int off=32; off; off>>=1) ss += __shfl_xor(ss, off, 64);
    __shared__ float red[4];
    if ((tid&63)==0) red[tid>>6] = ss;
    __syncthreads();
    float total = red[0]+red[1]+red[2]+red[3];
    float rs = rsqrtf(total*(1.f/512.f) + 1e-5f);
    float2 w2 = *(const float2*)&norm_w[tid*2];
    u16 h0,l0,h1,l1;
    splitbf(v.x*rs*w2.x, h0, l0);
    splitbf(v.y*rs*w2.y, h1, l1);
    *(unsigned*)&hbh[(size_t)m*512 + tid*2] = (unsigned)h0 | ((unsigned)h1<<16);
    *(unsigned*)&hbl[(size_t)m*512 + tid*2] = (unsigned)l0 | ((unsigned)l1<<16);
  } else if (blk < MR + WBLK) {
    int i = (blk - MR)*256 + tid;
    if (i >= TOT) return;
    float v;
    if (i < NIN)               v = f_in[i];
    else if (i < 2*NIN)        v = b_in[i-NIN];
    else if (i < 2*NIN+NOUT)   v = f_out[i-2*NIN];
    else if (i < 2*NIN+2*NOUT) v = b_out[i-2*NIN-NOUT];
    else                       v = proj[i-2*NIN-2*NOUT];
    if (i < 2*NIN) {
      u16 hh, ll; splitbf(v, hh, ll);
      H[i] = hh; L[i] = ll;
    } else {
      wpk[i - 2*NIN] = packbf(v);
    }
  } else {
    size_t i = ((size_t)(blk - MR - WBLK)*256 + tid)*4;   // 2048 blocks cover MR*512
    *(float4*)&out[i] = *(const float4*)&x[i];
  }
}

// ------- in_proj GEMM: 128x128 tile (z=2) + wcomb piggyback (y<2, dispatched first) -------
// XCD-aware remap: flat gemm id g preserves bid mod 8 (XCD lane); each lane
// sweeps all 18 n-tiles for one (dir, m-tile) A-panel before advancing ->
// A-panel stays hot in that XCD's L2. Bijective over (dir, m, n).
__global__ __launch_bounds__(256) void gemm_in(
    const u16* __restrict__ Ah, const u16* __restrict__ Al,
    const u16* __restrict__ Wh, const u16* __restrict__ Wl,
    float* __restrict__ C0,
    const unsigned* __restrict__ wpk,
    u16* __restrict__ Wch, u16* __restrict__ Wcl)
{
  constexpr int K = 512;
  constexpr int N = DIP;
  __shared__ __align__(16) u16 sAh[128*32];
  __shared__ __align__(16) u16 sAl[128*32];
  __shared__ __align__(16) u16 sBh[128*32];
  __shared__ __align__(16) u16 sBl[128*32];
  const int tid = threadIdx.x;
  if (blockIdx.y < 2) {
    // ---- wcomb body (dispatched early) ----
    int widx = blockIdx.y*64 + blockIdx.x*2 + blockIdx.z;  // 0..127
    int d = widx & 1;
    int p0 = ((widx>>1)&7)*128;
    int o0 = (widx>>4)*64;
    int wv = tid>>6, lane = tid&63;
    int quad = lane>>4, l16 = lane&15;
    const unsigned* owp = wpk + (size_t)d*NOUT;     // out_w_d [i][p]
    const unsigned* pjp = wpk + 2*(size_t)NOUT;     // proj [o][1024]
    int pc = p0 + wv*32;
    f32x4 acc[4][2] = {};
    for (int kt=0; kt<512; kt+=32) {
      bf16x8 ahf[4], alf[4], bhf[2], blf[2];
      #pragma unroll
      for (int ia=0; ia<4; ia++)
        unpack8(pjp + (size_t)(o0 + 16*ia + l16)*1024 + d*512 + kt + quad*8, ahf[ia], alf[ia]);
      #pragma unroll
      for (int jb=0; jb<2; jb++)
        unpack8s(owp + (size_t)(kt + quad*8)*1024 + pc + 16*jb + l16, 1024, bhf[jb], blf[jb]);
      #pragma unroll
      for (int ia=0; ia<4; ia++)
        #pragma unroll
        for (int jb=0; jb<2; jb++) {
          f32x4 t = __builtin_amdgcn_mfma_f32_16x16x32_bf16(ahf[ia], blf[jb], acc[ia][jb], 0,0,0);
          t       = __builtin_amdgcn_mfma_f32_16x16x32_bf16(alf[ia], bhf[jb], t,           0,0,0);
          acc[ia][jb] = __builtin_amdgcn_mfma_f32_16x16x32_bf16(ahf[ia], bhf[jb], t,       0,0,0);
        }
    }
    #pragma unroll
    for (int ia=0; ia<4; ia++)
    #pragma unroll
    for (int jb=0; jb<2; jb++)
    #pragma unroll
    for (int r=0; r<4; r++) {
      int o = o0 + 16*ia + quad*4 + r;
      int p = pc + 16*jb + l16;
      u16 hh, ll; splitbf(acc[ia][jb][r], hh, ll);
      Wch[(size_t)d*NOUT + (size_t)o*1024 + p] = hh;
      Wcl[(size_t)d*NOUT + (size_t)o*1024 + p] = ll;
    }
    return;
  }
  // ---- gemm body with XCD-aware work remap ----
  int g = blockIdx.x + 32*(blockIdx.y - 2) + 576*blockIdx.z;  // 0..1151
  int rl = g & 7, q = g >> 3;          // rl = XCD lane (bid mod 8 preserved)
  const int n0 = (q % 18) * 128;       // lane sweeps n for fixed A-panel
  int combo = (q / 18) * 8 + rl;       // 0..63 -> (dir, m-tile)
  const int dir = combo >> 5;
  const int m0 = (combo & 31) * 128;
  const int nvalid = N - n0;            // 128 for all tiles except last (16)
  const int lane = tid & 63;
  const int wid  = tid >> 6;
  const u16* wh_p = Wh + (size_t)dir*NIN;
  const u16* wl_p = Wl + (size_t)dir*NIN;
  const int j0 = wid, j1 = wid + 4;
  const int cp = lane & 3;
  auto goff = [&](int j, bool isB)->size_t {
    int row = 16*j + (lane>>2);
    int s = (row>>1) & 3;
    int kc = (cp ^ s) * 8;
    int grow;
    if (!isB) {
      grow = m0 + row;
      if (dir) grow = (grow & ~1023) + (1023 - (grow & 1023));  // seq flip
    } else {
      grow = n0 + row;
      if (grow >= N) grow = N-1;
    }
    return (size_t)grow*K + kc;
  };
  const size_t a0 = goff(j0,false), a1 = goff(j1,false);
  const size_t b0 = goff(j0,true),  b1 = goff(j1,true);
  const bool vB0 = (16*j0 < nvalid);    // B row-group j0 has a valid col
  const bool vB1 = (16*j1 < nvalid);
  const int wm = (wid & 1) * 64;
  const int wn = (wid >> 1) * 64;
  const int quad = lane >> 4;
  const int l16  = lane & 15;
  const int qx = quad ^ ((l16>>1)&3);
  const int baseA = ((wm + l16)*4 + qx)*8;
  const int baseB = ((wn + l16)*4 + qx)*8;
  f32x4 acc[4][4] = {};
  for (int kt = 0; kt < K; kt += 32) {
    __syncthreads();
    gl16(Ah + a0 + kt, &sAh[j0*512]);  gl16(Ah + a1 + kt, &sAh[j1*512]);
    gl16(Al + a0 + kt, &sAl[j0*512]);  gl16(Al + a1 + kt, &sAl[j1*512]);
    if (vB0) { gl16(wh_p + b0 + kt, &sBh[j0*512]);  gl16(wl_p + b0 + kt, &sBl[j0*512]); }
    if (vB1) { gl16(wh_p + b1 + kt, &sBh[j1*512]);  gl16(wl_p + b1 + kt, &sBl[j1*512]); }
    __syncthreads();
    bf16x8 ah[4], al[4], bh[4], bl[4];
    #pragma unroll
    for (int i=0;i<4;i++) {
      ah[i] = *(const bf16x8*)&sAh[baseA + i*512];
      al[i] = *(const bf16x8*)&sAl[baseA + i*512];
    }
    #pragma unroll
    for (int j=0;j<4;j++) {
      if (wn + 16*j < nvalid) {
        bh[j] = *(const bf16x8*)&sBh[baseB + j*512];
        bl[j] = *(const bf16x8*)&sBl[baseB + j*512];
      }
    }
    #pragma unroll
    for (int i=0;i<4;i++)
      #pragma unroll
      for (int j=0;j<4;j++) {
        if (wn + 16*j < nvalid) {
          f32x4 t = __builtin_amdgcn_mfma_f32_16x16x32_bf16(ah[i], bl[j], acc[i][j], 0,0,0);
          t       = __builtin_amdgcn_mfma_f32_16x16x32_bf16(al[i], bh[j], t,         0,0,0);
          acc[i][j] = __builtin_amdgcn_mfma_f32_16x16x32_bf16(ah[i], bh[j], t,       0,0,0);
        }
      }
  }
  #pragma unroll
  for (int i=0;i<4;i++)
  #pragma unroll
  for (int j=0;j<4;j++)
  #pragma unroll
  for (int r=0;r<4;r++) {
    int mo = m0 + wm + i*16 + quad*4 + r;
    int no = n0 + wn + j*16 + l16;
    if (no < N) C0[((size_t)dir*MR + mo)*DIP + no] = acc[i][j][r];
  }
}

// ------- final GEMM (z=dir, both dirs concurrent): 64x128 tile, 256 thr -------
__global__ __launch_bounds__(256) void gemm_final(
    const u16* __restrict__ zt, const u16* __restrict__ Wch, const u16* __restrict__ Wcl,
    float* __restrict__ out)
{
  constexpr int K = 1024;
  __shared__ __align__(16) u16 sAh[64*32];
  __shared__ __align__(16) u16 sAl[64*32];
  __shared__ __align__(16) u16 sBh[128*32];
  __shared__ __align__(16) u16 sBl[128*32];
  const int tid = threadIdx.x;
  const int dir = blockIdx.z;
  const int m0 = blockIdx.x * 64;
  const int n0 = blockIdx.y * 128;
  const int lane = tid & 63;
  const int wid  = tid >> 6;
  const u16* ah_p = zt + 2048 + (size_t)dir*MR*ZROW;
  const u16* al_p = zt + 3072 + (size_t)dir*MR*ZROW;
  const u16* wh_p = Wch + (size_t)dir*NOUT;
  const u16* wl_p = Wcl + (size_t)dir*NOUT;
  const int cp = lane & 3;
  auto goffA = [&](int j)->size_t {
    int row = 16*j + (lane>>2);
    int s = (row>>1) & 3;
    int kc = (cp ^ s) * 8;
    int grow = m0 + row;
    if (dir) grow = (grow & ~1023) + (1023 - (grow & 1023));  // read flipped row
    return (size_t)grow*ZROW + kc;
  };
  auto goffB = [&](int j)->size_t {
    int row = 16*j + (lane>>2);
    int s = (row>>1) & 3;
    int kc = (cp ^ s) * 8;
    return (size_t)(n0 + row)*1024 + kc;
  };
  const size_t a0 = goffA(wid);
  const size_t b0 = goffB(wid), b1 = goffB(wid+4);
  const int quad = lane >> 4;
  const int l16  = lane & 15;
  const int qx = quad ^ ((l16>>1)&3);
  const int baseA = (l16*4 + qx)*8;
  const int baseB = ((wid*32 + l16)*4 + qx)*8;
  f32x4 acc[4][2] = {};
  for (int kt = 0; kt < K; kt += 32) {
    __syncthreads();
    gl16(ah_p + a0 + kt, &sAh[wid*512]);
    gl16(al_p + a0 + kt, &sAl[wid*512]);
    gl16(wh_p + b0 + kt, &sBh[wid*512]);  gl16(wh_p + b1 + kt, &sBh[(wid+4)*512]);
    gl16(wl_p + b0 + kt, &sBl[wid*512]);  gl16(wl_p + b1 + kt, &sBl[(wid+4)*512]);
    __syncthreads();
    bf16x8 ah[4], al[4], bh[2], bl[2];
    #pragma unroll
    for (int i=0;i<4;i++) {
      ah[i] = *(const bf16x8*)&sAh[baseA + i*512];
      al[i] = *(const bf16x8*)&sAl[baseA + i*512];
    }
    #pragma unroll
    for (int j=0;j<2;j++) {
      bh[j] = *(const bf16x8*)&sBh[baseB + j*512];
      bl[j] = *(const bf16x8*)&sBl[baseB + j*512];
    }
    #pragma unroll
    for (int i=0;i<4;i++)
      #pragma unroll
      for (int j=0;j<2;j++) {
        f32x4 t = __builtin_amdgcn_mfma_f32_16x16x32_bf16(ah[i], bl[j], acc[i][j], 0,0,0);
        t       = __builtin_amdgcn_mfma_f32_16x16x32_bf16(al[i], bh[j], t,         0,0,0);
        acc[i][j] = __builtin_amdgcn_mfma_f32_16x16x32_bf16(ah[i], bh[j], t,       0,0,0);
      }
  }
  #pragma unroll
  for (int i=0;i<4;i++)
  #pragma unroll
  for (int j=0;j<2;j++)
  #pragma unroll
  for (int r=0;r<4;r++) {
    int mo = m0 + i*16 + quad*4 + r;
    int no = n0 + wid*32 + j*16 + l16;
    atomicAdd(&out[(size_t)mo*512 + no], acc[i][j][r]);
  }
}

// ---------------- K3: depthwise conv + SiLU + dt softplus ----------------
// 8 output rows per block: 11-row register window slides across 8 outputs.
__global__ __launch_bounds__(320) void conv_dt(
  const float* __restrict__ Z,
  const float* __restrict__ f_cw, const float* __restrict__ f_cb,
  const float* __restrict__ b_cw, const float* __restrict__ b_cb,
  const float* __restrict__ f_dtb, const float* __restrict__ b_dtb,
  unsigned* __restrict__ xconv,
  unsigned* __restrict__ Bc, unsigned* __restrict__ Cc,
  float* __restrict__ dtq)
{
  int bsw = blockIdx.x;
  int b = (bsw & 7)*128 + (bsw >> 3);   // bijective XCD remap (1024 = 8*128)
  int r0 = b*8;                         // rows r0..r0+7: same dir, same sequence
  int dir = r0 >> 12;
  int t0 = r0 & 1023;
  const float* cw  = dir ? b_cw : f_cw;
  const float* cb  = dir ? b_cb : f_cb;
  const float* dtb = dir ? b_dtb : f_dtb;
  int tid = threadIdx.x;
  if (tid < 288) {
    int c0 = tid*4;
    float4 w0 = *(const float4*)&cw[c0*4];
    float4 w1 = *(const float4*)&cw[(c0+1)*4];
    float4 w2 = *(const float4*)&cw[(c0+2)*4];
    float4 w3 = *(const float4*)&cw[(c0+3)*4];
    float4 cb4 = *(const float4*)&cb[c0];
    const float4 zero4 = {0.f,0.f,0.f,0.f};
    float4 wnd[11];
    #pragma unroll
    for (int j=0;j<11;j++) {
      int a = r0 - 3 + j;
      wnd[j] = (a >= 0) ? *(const float4*)(Z + (size_t)a*DIP + 1024 + c0) : zero4;
    }
    #pragma unroll
    for (int k=0;k<8;k++) {
      int t = t0 + k;
      float4 z0 = (t >= 3) ? wnd[k]   : zero4;
      float4 z1 = (t >= 2) ? wnd[k+1] : zero4;
      float4 z2 = (t >= 1) ? wnd[k+2] : zero4;
      float4 z3 = wnd[k+3];
      float4 a = cb4;
      a.x += z0.x*w0.x + z1.x*w0.y + z2.x*w0.z + z3.x*w0.w;
      a.y += z0.y*w1.x + z1.y*w1.y + z2.y*w1.z + z3.y*w1.w;
      a.z += z0.z*w2.x + z1.z*w2.y + z2.z*w2.z + z3.z*w2.w;
      a.w += z0.w*w3.x + z1.w*w3.y + z2.w*w3.z + z3.w*w3.w;
      float4 v;
      v.x = a.x * sigm(a.x); v.y = a.y * sigm(a.y);
      v.z = a.z * sigm(a.z); v.w = a.w * sigm(a.w);
      uint4 pv;
      pv.x = packbf(v.x); pv.y = packbf(v.y);
      pv.z = packbf(v.z); pv.w = packbf(v.w);
      int bm = r0 + k;
      if (c0 < 1024)      *(uint4*)&xconv[(size_t)bm*DI + c0] = pv;
      else if (c0 < 1088) *(uint4*)&Bc[(size_t)bm*64 + (c0-1024)] = pv;
      else                *(uint4*)&Cc[(size_t)bm*64 + (c0-1088)] = pv;
    }
  }
  if (tid < NH) {
    #pragma unroll
    for (int k=0;k<8;k++) {
      int bm = r0 + k;
      float dtraw = Z[(size_t)bm*DIP + 2176 + tid] + dtb[tid];
      float dt = (dtraw > 20.f) ? dtraw : log1pf(__expf(dtraw));
      dtq[(size_t)bm*NH + tid] = dt;
    }
  }
}

// ---------- K4a: S-only chunk kernel ----------
__global__ __launch_bounds__(256) void scan_mfma(
  const float* __restrict__ dtq, const unsigned* __restrict__ xconv,
  const unsigned* __restrict__ Bc,
  const float* __restrict__ f_Al, const float* __restrict__ b_Al,
  float* __restrict__ cumdec, float* __restrict__ S)
{
  __shared__ float scum[4][32];
  __shared__ float sdt[4][32];
  int bx = blockIdx.x;
  int hq = bx & 3, chunk = (bx>>2)&(NCH-1), dirb = bx>>7;
  int w = threadIdx.x >> 6, lane = threadIdx.x & 63;
  int h = hq*4 + w;
  int base_row = dirb*1024 + chunk*CT;
  const int quad = lane >> 4, l16 = lane & 15;
  const float* Al = (dirb >= 4) ? b_Al : f_Al;
  float A = -__expf(Al[h]);
  float dtl = 0.f, cum = 0.f;
  if (lane < 32) { dtl = dtq[(size_t)(base_row + lane)*16 + h]; cum = dtl; }
  #pragma unroll
  for (int off=1; off<32; off<<=1) {
    int src = (lane >= off) ? lane-off : lane;
    float o = __shfl(cum, src);
    if (lane >= off && lane < 32) cum += o;
  }
  if (lane < 32) {
    sdt[w][lane]  = dtl;
    scum[w][lane] = cum;
    cumdec[(size_t)(base_row + lane)*16 + h] = __expf(A*cum);
  }
  // ---- X^T fragments ----
  bf16x8 xhf[4], xlf[4];
  const unsigned* xp = xconv + (size_t)(base_row + quad*8)*1024 + h*64 + l16;
  #pragma unroll
  for (int jp=0;jp<4;jp++) unpack8s(xp + 16*jp, 1024, xhf[jp], xlf[jp]);
  // ---- S^T = X^T @ (w.B)^T ----
  float wv[8];
  float ct31 = scum[w][31];
  #pragma unroll
  for (int jj=0;jj<8;jj++) {
    int s = quad*8 + jj;
    wv[jj] = sdt[w][s] * __expf(A*(ct31 - scum[w][s]));
  }
  bf16x8 wbh[4], wbl[4];
  #pragma unroll
  for (int j2=0;j2<4;j2++) {
    u16x8 hu, lu; u16 hh, ll;
    #pragma unroll
    for (int jj=0;jj<8;jj++) {
      float b = unpackf(Bc[(size_t)(base_row + quad*8 + jj)*64 + 16*j2 + l16]);
      splitbf(wv[jj]*b, hh, ll); hu[jj]=hh; lu[jj]=ll;
    }
    wbh[j2] = __builtin_bit_cast(bf16x8, hu);
    wbl[j2] = __builtin_bit_cast(bf16x8, lu);
  }
  size_t inst = ((size_t)(dirb*16+h)*NCH + chunk)*4096;
  __builtin_amdgcn_s_setprio(1);
  #pragma unroll
  for (int mp=0;mp<4;mp++)
  #pragma unroll
  for (int j2=0;j2<4;j2++) {
    f32x4 acc = {};
    acc = __builtin_amdgcn_mfma_f32_16x16x32_bf16(xhf[mp], wbl[j2], acc, 0,0,0);
    acc = __builtin_amdgcn_mfma_f32_16x16x32_bf16(xlf[mp], wbh[j2], acc, 0,0,0);
    acc = __builtin_amdgcn_mfma_f32_16x16x32_bf16(xhf[mp], wbh[j2], acc, 0,0,0);
    #pragma unroll
    for (int r=0;r<4;r++)
      S[inst + (size_t)(16*mp + quad*4 + r)*64 + 16*j2 + l16] = acc[r];
  }
  __builtin_amdgcn_s_setprio(0);
}

// ---------- K4b: inter-chunk combine; S[c] overwritten with PACKED h_start(c) ----------
__global__ __launch_bounds__(256) void scan_comb(
  const float* __restrict__ cumdec, float* __restrict__ S)
{
  int ih = blockIdx.x >> 4;            // dirb*16 + h
  int sub = blockIdx.x & 15;
  int dirb = ih >> 4, h = ih & 15;
  int elem = sub*256 + threadIdx.x;    // 0..4095 = p*64+n
  size_t base = (size_t)ih*NCH*4096 + elem;
  float hr = 0.f;
  #pragma unroll
  for (int c=0;c<NCH;c++) {
    float P = cumdec[((size_t)(dirb*1024 + c*CT + CT-1))*16 + h];
    float s = S[base + c*4096];
    S[base + c*4096] = __builtin_bit_cast(float, packbf(hr));  // packed h_start
    hr = fmaf(hr, P, s);
  }
}

// ---------- K4c: fused G/M/Y1 + Y2 + gate + rmsnorm ----------
__global__ __launch_bounds__(1024) void scan_y2_gate(
  const unsigned* __restrict__ Cc, const unsigned* __restrict__ Bc,
  const float* __restrict__ S, const unsigned* __restrict__ xconv,
  const float* Z, u16* zt, const float* __restrict__ dtq,
  const float* __restrict__ f_Al, const float* __restrict__ b_Al,
  const float* __restrict__ f_D, const float* __restrict__ b_D,
  const float* __restrict__ f_gw, const float* __restrict__ b_gw)
{
  __shared__ __align__(16) u16 sMh[16][32*40];
  __shared__ __align__(16) u16 sMl[16][32*40];
  __shared__ float sdt2[16][32];
  __shared__ float scum2[16][32];
  __shared__ float red[32][17];
  __shared__ float rsb[32];
  int bx = blockIdx.x;
  int chunk = bx & (NCH-1), dirb = bx >> 5;
  int w = threadIdx.x >> 6, lane = threadIdx.x & 63;
  int h = w;
  int dir = dirb >> 2;
  int row0 = dirb*1024 + chunk*CT;
  const int quad = lane>>4, l16 = lane&15;
  const float* Alp = (dirb >= 4) ? b_Al : f_Al;
  const float* Dp  = dir ? b_D  : f_D;
  const float* gwp = dir ? b_gw : f_gw;
  float A = -__expf(Alp[h]);
  float Dv = Dp[h];
  // dt + prefix (lanes 0..31) -> per-head LDS
  float dtl = 0.f, cum = 0.f;
  if (lane < 32) { dtl = dtq[(size_t)(row0 + lane)*16 + h]; cum = dtl; }
  #pragma unroll
  for (int off=1; off<32; off<<=1) {
    int src = (lane >= off) ? lane-off : lane;
    float o = __shfl(cum, src);
    if (lane >= off && lane < 32) cum += o;
  }
  if (lane < 32) { sdt2[h][lane] = dtl; scum2[h][lane] = cum; }
  // ---- G = C @ B^T (C frags stay live for Y2) ----
  bf16x8 chf[2][2], clf[2][2];
  f32x4 g[2][2];
  {
    bf16x8 bhf[2][2], blf[2][2];
    #pragma unroll
    for (int i=0;i<2;i++)
    #pragma unroll
    for (int kk=0;kk<2;kk++) {
      unpack8(Cc + (size_t)(row0 + 16*i + l16)*64 + kk*32 + quad*8, chf[i][kk], clf[i][kk]);
      unpack8(Bc + (size_t)(row0 + 16*i + l16)*64 + kk*32 + quad*8, bhf[i][kk], blf[i][kk]);
    }
    __builtin_amdgcn_s_setprio(1);
    #pragma unroll
    for (int i=0;i<2;i++)
    #pragma unroll
    for (int j=0;j<2;j++) {
      f32x4 acc = {};
      #pragma unroll
      for (int kk=0;kk<2;kk++) {
        acc = __builtin_amdgcn_mfma_f32_16x16x32_bf16(chf[i][kk], blf[j][kk], acc, 0,0,0);
        acc = __builtin_amdgcn_mfma_f32_16x16x32_bf16(clf[i][kk], bhf[j][kk], acc, 0,0,0);
        acc = __builtin_amdgcn_mfma_f32_16x16x32_bf16(chf[i][kk], bhf[j][kk], acc, 0,0,0);
      }
      g[i][j] = acc;
    }
    __builtin_amdgcn_s_setprio(0);
  }
  // ---- mask -> M, write split-bf16 to per-head sM ----
  float ctt[2][4];
  #pragma unroll
  for (int i=0;i<2;i++)
  #pragma unroll
  for (int r=0;r<4;r++) ctt[i][r] = scum2[h][16*i + quad*4 + r];
  #pragma unroll
  for (int j=0;j<2;j++) {
    int s = 16*j + l16;
    float cts = scum2[h][s];
    float dts = sdt2[h][s];
    #pragma unroll
    for (int i=0;i<2;i++)
    #pragma unroll
    for (int r=0;r<4;r++) {
      int t = 16*i + quad*4 + r;
      float mv = (s <= t) ? g[i][j][r] * __expf(A*(ctt[i][r]-cts)) * dts : 0.f;
      u16 hh, ll; splitbf(mv, hh, ll);
      sMh[h][t*40 + s] = hh;
      sMl[h][t*40 + s] = ll;
    }
  }
  // at = exp(A*cum) per output row
  float at[2][4];
  #pragma unroll
  for (int i=0;i<2;i++)
  #pragma unroll
  for (int r=0;r<4;r++) at[i][r] = __expf(A*ctt[i][r]);
  // ---- acc = at * (C @ h_start^T)  (chunk>0) ----
  f32x4 acc[2][4] = {};
  if (chunk > 0) {
    size_t inst = ((size_t)(dirb*16+h)*NCH + chunk)*4096;
    const unsigned* Sp = (const unsigned*)S;
    __builtin_amdgcn_s_setprio(1);
    #pragma unroll
    for (int j=0;j<4;j++) {
      bf16x8 hhf[2], hlf[2];
      #pragma unroll
      for (int kk=0;kk<2;kk++)
        unpack8(Sp + inst + (size_t)(16*j + l16)*64 + kk*32 + quad*8, hhf[kk], hlf[kk]);
      #pragma unroll
      for (int i=0;i<2;i++) {
        f32x4 a2 = {};
        #pragma unroll
        for (int kk=0;kk<2;kk++) {
          a2 = __builtin_amdgcn_mfma_f32_16x16x32_bf16(chf[i][kk], hlf[kk], a2, 0,0,0);
          a2 = __builtin_amdgcn_mfma_f32_16x16x32_bf16(clf[i][kk], hhf[kk], a2, 0,0,0);
          a2 = __builtin_amdgcn_mfma_f32_16x16x32_bf16(chf[i][kk], hhf[kk], a2, 0,0,0);
        }
        #pragma unroll
        for (int r=0;r<4;r++) acc[i][j][r] = at[i][r]*a2[r];
      }
    }
    __builtin_amdgcn_s_setprio(0);
  }
  // ---- Y1 = M @ X accumulated on top ----
  {
    bf16x8 xhf[4], xlf[4];
    const unsigned* xp = xconv + (size_t)(row0 + quad*8)*1024 + h*64 + l16;
    #pragma unroll
    for (int jp=0;jp<4;jp++) unpack8s(xp + 16*jp, 1024, xhf[jp], xlf[jp]);
    bf16x8 mhf[2], mlf[2];
    #pragma unroll
    for (int i=0;i<2;i++) {
      mhf[i] = *(const bf16x8*)&sMh[h][(16*i + l16)*40 + quad*8];
      mlf[i] = *(const bf16x8*)&sMl[h][(16*i + l16)*40 + quad*8];
    }
    __builtin_amdgcn_s_setprio(1);
    #pragma unroll
    for (int i=0;i<2;i++)
    #pragma unroll
    for (int jp=0;jp<4;jp++) {
      f32x4 a2 = acc[i][jp];
      a2 = __builtin_amdgcn_mfma_f32_16x16x32_bf16(mhf[i], xlf[jp], a2, 0,0,0);
      a2 = __builtin_amdgcn_mfma_f32_16x16x32_bf16(mlf[i], xhf[jp], a2, 0,0,0);
      a2 = __builtin_amdgcn_mfma_f32_16x16x32_bf16(mhf[i], xhf[jp], a2, 0,0,0);
      acc[i][jp] = a2;
    }
    __builtin_amdgcn_s_setprio(0);
  }
  // ---- gate: v = (y + x*D) * silu(z), v overwrites acc ----
  float pss[2][4] = {};
  #pragma unroll
  for (int i=0;i<2;i++)
  #pragma unroll
  for (int r=0;r<4;r++) {
    int t = 16*i + quad*4 + r;
    size_t gg = (size_t)(row0 + t);
    #pragma unroll
    for (int j=0;j<4;j++) {
      int c = h*64 + 16*j + l16;
      float xv = unpackf(xconv[gg*1024 + c]);
      float zv = Z[gg*DIP + c];
      float v = (acc[i][j][r] + xv*Dv) * (zv * sigm(zv));
      acc[i][j][r] = v;
      pss[i][r] += v*v;
    }
  }
  #pragma unroll
  for (int i=0;i<2;i++)
  #pragma unroll
  for (int r=0;r<4;r++) {
    float s2 = pss[i][r];
    s2 += __shfl_xor(s2, 1, 64);
    s2 += __shfl_xor(s2, 2, 64);
    s2 += __shfl_xor(s2, 4, 64);
    s2 += __shfl_xor(s2, 8, 64);
    if (l16 == 0) red[16*i + quad*4 + r][w] = s2;
  }
  __syncthreads();
  if (threadIdx.x < 32) {
    int t = threadIdx.x;
    float tot = 0.f;
    #pragma unroll
    for (int ww=0; ww<16; ww++) tot += red[t][ww];
    rsb[t] = rsqrtf(tot*(1.f/1024.f) + 1e-5f);
  }
  __syncthreads();
  // normalize + write split planes into Z-tail
  #pragma unroll
  for (int i=0;i<2;i++)
  #pragma unroll
  for (int r=0;r<4;r++) {
    int t = 16*i + quad*4 + r;
    size_t gg = (size_t)(row0 + t);
    float rs = rsb[t];
    #pragma unroll
    for (int j=0;j<4;j++) {
      int c = h*64 + 16*j + l16;
      float o = acc[i][j][r] * rs * gwp[c];
      u16 hh, ll; splitbf(o, hh, ll);
      zt[gg*ZROW + 2048 + c] = hh;
      zt[gg*ZROW + 3072 + c] = ll;
    }
  }
}

extern "C" void kernel_launch(void* const* d_in, const int* in_sizes, int n_in,
                              void* d_out, int out_size, void* d_ws, size_t ws_size,
                              hipStream_t stream)
{
  const float* x        = (const float*)d_in[0];
  const float* norm_w   = (const float*)d_in[1];
  const float* f_in_w   = (const float*)d_in[2];
  const float* f_conv_w = (const float*)d_in[3];
  const float* f_conv_b = (const float*)d_in[4];
  const float* f_dt_bias= (const float*)d_in[5];
  const float* f_A_log  = (const float*)d_in[6];
  const float* f_D      = (const float*)d_in[7];
  const float* f_gw     = (const float*)d_in[8];
  const float* f_out_w  = (const float*)d_in[9];
  const float* b_in_w   = (const float*)d_in[10];
  const float* b_conv_w = (const float*)d_in[11];
  const float* b_conv_b = (const float*)d_in[12];
  const float* b_dt_bias= (const float*)d_in[13];
  const float* b_A_log  = (const float*)d_in[14];
  const float* b_D      = (const float*)d_in[15];
  const float* b_gw     = (const float*)d_in[16];
  const float* b_out_w  = (const float*)d_in[17];
  const float* proj_w   = (const float*)d_in[18];

  char* ws = (char*)d_ws;
  size_t off = 0;
  auto alloc = [&](size_t bytes)->char* {
    char* p = ws + off; off = (off + bytes + 255) & ~(size_t)255; return p;
  };
  u16*   hbh   = (u16*)  alloc((size_t)MR*512*2);
  u16*   hbl   = (u16*)  alloc((size_t)MR*512*2);
  u16*   wH    = (u16*)  alloc(2*(size_t)NIN*2);
  u16*   wL    = (u16*)  alloc(2*(size_t)NIN*2);
  unsigned* wpk = (unsigned*)alloc(3*(size_t)NOUT*4);
  u16*   Wch   = (u16*)  alloc(2*(size_t)NOUT*2);
  u16*   Wcl   = (u16*)  alloc(2*(size_t)NOUT*2);
  float* Z     = (float*)alloc(2*(size_t)MR*DIP*4);
  unsigned* xconv = (unsigned*)alloc(2*(size_t)MR*DI*4);
  unsigned* Bc    = (unsigned*)alloc(2*(size_t)MR*64*4);
  unsigned* Cc    = (unsigned*)alloc(2*(size_t)MR*64*4);
  float* dtq   = (float*)alloc(2*(size_t)MR*NH*4);
  float* cumdec= (float*)alloc(2*(size_t)MR*NH*4);
  float* S     = (float*)alloc((size_t)4096*4096*4);
  u16* wih = wH;  u16* wil = wL;
  // yg planes live in the dead xBC tails of Z rows (see ZROW).

  constexpr int TOT = 2*NIN + 3*NOUT;
  constexpr int WBLK = (TOT + 255)/256;
  prep<<<MR + WBLK + 2048,256,0,stream>>>(x, norm_w, f_in_w, b_in_w,
                                          f_out_w, b_out_w, proj_w,
                                          wH, wL, wpk, hbh, hbl, (float*)d_out);
  gemm_in<<<dim3(32,20,2),256,0,stream>>>(hbh, hbl, wih, wil, Z, wpk, Wch, Wcl);
  conv_dt<<<1024,320,0,stream>>>(Z, f_conv_w, f_conv_b, b_conv_w, b_conv_b,
                                 f_dt_bias, b_dt_bias, xconv, Bc, Cc, dtq);
  scan_mfma<<<1024,256,0,stream>>>(dtq, xconv, Bc, f_A_log, b_A_log, cumdec, S);
  scan_comb<<<2048,256,0,stream>>>(cumdec, S);
  scan_y2_gate<<<256,1024,0,stream>>>(Cc, Bc, S, xconv, Z, (u16*)Z, dtq,
                                      f_A_log, b_A_log, f_D, b_D, f_gw, b_gw);
  gemm_final<<<dim3(64,4,2),256,0,stream>>>((u16*)Z, Wch, Wcl, (float*)d_out);
}

// Round 14
// 315.794 us; speedup vs baseline: 1.0238x; 1.0238x over previous
//
#include <hip/hip_runtime.h>
#include <math.h>

typedef unsigned short u16;
typedef __bf16  bf16x8 __attribute__((ext_vector_type(8)));
typedef float   f32x4  __attribute__((ext_vector_type(4)));
typedef unsigned short u16x8 __attribute__((ext_vector_type(8)));

#define SEQ 1024
#define MR  4096          // BATCH*SEQ rows
#define DIP 2192          // in_proj output width
#define DI  1024          // d_inner
#define NH  16
#define CD  1152          // conv dim
#define NCH 32            // chunks per sequence
#define CT  32            // timesteps per chunk
#define NIN (DIP*512)
#define NOUT (512*1024)
// ygh/ygl live in the dead xBC tail of Z rows: row stride 4384 u16,
// hi plane at +2048, lo plane at +3072 (u16 units)
#define ZROW 4384

__device__ __forceinline__ u16 f2bf(float f) {
  union { float f; unsigned u; } v; v.f = f;
  unsigned r = v.u + 0x7FFFu + ((v.u >> 16) & 1u);
  return (u16)(r >> 16);
}
__device__ __forceinline__ float bf2f(u16 h) {
  union { unsigned u; float f; } v; v.u = ((unsigned)h) << 16; return v.f;
}
__device__ __forceinline__ void splitbf(float v, u16& h, u16& l) {
  h = f2bf(v); l = f2bf(v - bf2f(h));
}
__device__ __forceinline__ float sigm(float x){ return 1.f/(1.f+__expf(-x)); }

// pack split-bf16 pair into one u32: hi in [15:0], lo in [31:16]
__device__ __forceinline__ unsigned packbf(float v) {
  u16 hh, ll; splitbf(v, hh, ll);
  return (unsigned)hh | ((unsigned)ll << 16);
}
__device__ __forceinline__ float unpackf(unsigned w) {
  return bf2f((u16)w) + bf2f((u16)(w >> 16));
}

// unpack 8 contiguous packed u32 -> hi/lo bf16x8 fragments
__device__ __forceinline__ void unpack8(const unsigned* p, bf16x8& H, bf16x8& L) {
  uint4 a = *(const uint4*)p, b = *(const uint4*)(p+4);
  u16x8 hu, lu;
  hu[0]=(u16)a.x; lu[0]=(u16)(a.x>>16);
  hu[1]=(u16)a.y; lu[1]=(u16)(a.y>>16);
  hu[2]=(u16)a.z; lu[2]=(u16)(a.z>>16);
  hu[3]=(u16)a.w; lu[3]=(u16)(a.w>>16);
  hu[4]=(u16)b.x; lu[4]=(u16)(b.x>>16);
  hu[5]=(u16)b.y; lu[5]=(u16)(b.y>>16);
  hu[6]=(u16)b.z; lu[6]=(u16)(b.z>>16);
  hu[7]=(u16)b.w; lu[7]=(u16)(b.w>>16);
  H = __builtin_bit_cast(bf16x8, hu);
  L = __builtin_bit_cast(bf16x8, lu);
}
// unpack 8 strided packed u32 -> hi/lo bf16x8
__device__ __forceinline__ void unpack8s(const unsigned* p, int stride, bf16x8& H, bf16x8& L) {
  u16x8 hu, lu;
  #pragma unroll
  for (int jj=0;jj<8;jj++){ unsigned w = p[(size_t)jj*stride]; hu[jj]=(u16)w; lu[jj]=(u16)(w>>16); }
  H = __builtin_bit_cast(bf16x8, hu);
  L = __builtin_bit_cast(bf16x8, lu);
}

// async global->LDS, 16B per lane
__device__ __forceinline__ void gl16(const u16* g, u16* l) {
  __builtin_amdgcn_global_load_lds((const __attribute__((address_space(1))) void*)g,
                                   (__attribute__((address_space(3))) void*)l,
                                   16, 0, 0);
}

// ---------------- K0: fused prep = rmsnorm(x) + weight cast + out seed ----------------
__global__ __launch_bounds__(256) void prep(
  const float* __restrict__ x, const float* __restrict__ norm_w,
  const float* __restrict__ f_in, const float* __restrict__ b_in,
  const float* __restrict__ f_out, const float* __restrict__ b_out,
  const float* __restrict__ proj,
  u16* __restrict__ H, u16* __restrict__ L, unsigned* __restrict__ wpk,
  u16* __restrict__ hbh, u16* __restrict__ hbl, float* __restrict__ out)
{
  constexpr int TOT = 2*NIN + 3*NOUT;
  constexpr int WBLK = (TOT + 255)/256;
  int blk = blockIdx.x, tid = threadIdx.x;
  if (blk < MR) {
    int m = blk;
    const float* xr = x + (size_t)m*512;
    float2 v = *(const float2*)&xr[tid*2];
    float ss = v.x*v.x + v.y*v.y;
    #pragma unroll
    for (int off=32; off; off>>=1) ss += __shfl_xor(ss, off, 64);
    __shared__ float red[4];
    if ((tid&63)==0) red[tid>>6] = ss;
    __syncthreads();
    float total = red[0]+red[1]+red[2]+red[3];
    float rs = rsqrtf(total*(1.f/512.f) + 1e-5f);
    float2 w2 = *(const float2*)&norm_w[tid*2];
    u16 h0,l0,h1,l1;
    splitbf(v.x*rs*w2.x, h0, l0);
    splitbf(v.y*rs*w2.y, h1, l1);
    *(unsigned*)&hbh[(size_t)m*512 + tid*2] = (unsigned)h0 | ((unsigned)h1<<16);
    *(unsigned*)&hbl[(size_t)m*512 + tid*2] = (unsigned)l0 | ((unsigned)l1<<16);
  } else if (blk < MR + WBLK) {
    int i = (blk - MR)*256 + tid;
    if (i >= TOT) return;
    float v;
    if (i < NIN)               v = f_in[i];
    else if (i < 2*NIN)        v = b_in[i-NIN];
    else if (i < 2*NIN+NOUT)   v = f_out[i-2*NIN];
    else if (i < 2*NIN+2*NOUT) v = b_out[i-2*NIN-NOUT];
    else                       v = proj[i-2*NIN-2*NOUT];
    if (i < 2*NIN) {
      u16 hh, ll; splitbf(v, hh, ll);
      H[i] = hh; L[i] = ll;
    } else {
      wpk[i - 2*NIN] = packbf(v);
    }
  } else {
    size_t i = ((size_t)(blk - MR - WBLK)*256 + tid)*4;   // 2048 blocks cover MR*512
    *(float4*)&out[i] = *(const float4*)&x[i];
  }
}

// ------- in_proj GEMM: 128x128 tile (z=2) + wcomb piggyback (y<2, dispatched first) -------
// Natural n-major mapping (r12 form — measured best; XCD remap regressed, r13).
__global__ __launch_bounds__(256) void gemm_in(
    const u16* __restrict__ Ah, const u16* __restrict__ Al,
    const u16* __restrict__ Wh, const u16* __restrict__ Wl,
    float* __restrict__ C0,
    const unsigned* __restrict__ wpk,
    u16* __restrict__ Wch, u16* __restrict__ Wcl)
{
  constexpr int K = 512;
  constexpr int N = DIP;
  __shared__ __align__(16) u16 sAh[128*32];
  __shared__ __align__(16) u16 sAl[128*32];
  __shared__ __align__(16) u16 sBh[128*32];
  __shared__ __align__(16) u16 sBl[128*32];
  const int tid = threadIdx.x;
  if (blockIdx.y < 2) {
    // ---- wcomb body (dispatched early) ----
    int widx = blockIdx.y*64 + blockIdx.x*2 + blockIdx.z;  // 0..127
    int d = widx & 1;
    int p0 = ((widx>>1)&7)*128;
    int o0 = (widx>>4)*64;
    int wv = tid>>6, lane = tid&63;
    int quad = lane>>4, l16 = lane&15;
    const unsigned* owp = wpk + (size_t)d*NOUT;     // out_w_d [i][p]
    const unsigned* pjp = wpk + 2*(size_t)NOUT;     // proj [o][1024]
    int pc = p0 + wv*32;
    f32x4 acc[4][2] = {};
    for (int kt=0; kt<512; kt+=32) {
      bf16x8 ahf[4], alf[4], bhf[2], blf[2];
      #pragma unroll
      for (int ia=0; ia<4; ia++)
        unpack8(pjp + (size_t)(o0 + 16*ia + l16)*1024 + d*512 + kt + quad*8, ahf[ia], alf[ia]);
      #pragma unroll
      for (int jb=0; jb<2; jb++)
        unpack8s(owp + (size_t)(kt + quad*8)*1024 + pc + 16*jb + l16, 1024, bhf[jb], blf[jb]);
      #pragma unroll
      for (int ia=0; ia<4; ia++)
        #pragma unroll
        for (int jb=0; jb<2; jb++) {
          f32x4 t = __builtin_amdgcn_mfma_f32_16x16x32_bf16(ahf[ia], blf[jb], acc[ia][jb], 0,0,0);
          t       = __builtin_amdgcn_mfma_f32_16x16x32_bf16(alf[ia], bhf[jb], t,           0,0,0);
          acc[ia][jb] = __builtin_amdgcn_mfma_f32_16x16x32_bf16(ahf[ia], bhf[jb], t,       0,0,0);
        }
    }
    #pragma unroll
    for (int ia=0; ia<4; ia++)
    #pragma unroll
    for (int jb=0; jb<2; jb++)
    #pragma unroll
    for (int r=0; r<4; r++) {
      int o = o0 + 16*ia + quad*4 + r;
      int p = pc + 16*jb + l16;
      u16 hh, ll; splitbf(acc[ia][jb][r], hh, ll);
      Wch[(size_t)d*NOUT + (size_t)o*1024 + p] = hh;
      Wcl[(size_t)d*NOUT + (size_t)o*1024 + p] = ll;
    }
    return;
  }
  // ---- gemm body ----
  const int dir = blockIdx.z;
  const int m0 = blockIdx.x * 128;
  const int n0 = (blockIdx.y - 2) * 128;
  const int nvalid = N - n0;            // 128 for all tiles except last (16)
  const int lane = tid & 63;
  const int wid  = tid >> 6;
  const u16* wh_p = Wh + (size_t)dir*NIN;
  const u16* wl_p = Wl + (size_t)dir*NIN;
  const int j0 = wid, j1 = wid + 4;
  const int cp = lane & 3;
  auto goff = [&](int j, bool isB)->size_t {
    int row = 16*j + (lane>>2);
    int s = (row>>1) & 3;
    int kc = (cp ^ s) * 8;
    int grow;
    if (!isB) {
      grow = m0 + row;
      if (dir) grow = (grow & ~1023) + (1023 - (grow & 1023));  // seq flip
    } else {
      grow = n0 + row;
      if (grow >= N) grow = N-1;
    }
    return (size_t)grow*K + kc;
  };
  const size_t a0 = goff(j0,false), a1 = goff(j1,false);
  const size_t b0 = goff(j0,true),  b1 = goff(j1,true);
  const bool vB0 = (16*j0 < nvalid);    // B row-group j0 has a valid col
  const bool vB1 = (16*j1 < nvalid);
  const int wm = (wid & 1) * 64;
  const int wn = (wid >> 1) * 64;
  const int quad = lane >> 4;
  const int l16  = lane & 15;
  const int qx = quad ^ ((l16>>1)&3);
  const int baseA = ((wm + l16)*4 + qx)*8;
  const int baseB = ((wn + l16)*4 + qx)*8;
  f32x4 acc[4][4] = {};
  for (int kt = 0; kt < K; kt += 32) {
    __syncthreads();
    gl16(Ah + a0 + kt, &sAh[j0*512]);  gl16(Ah + a1 + kt, &sAh[j1*512]);
    gl16(Al + a0 + kt, &sAl[j0*512]);  gl16(Al + a1 + kt, &sAl[j1*512]);
    if (vB0) { gl16(wh_p + b0 + kt, &sBh[j0*512]);  gl16(wl_p + b0 + kt, &sBl[j0*512]); }
    if (vB1) { gl16(wh_p + b1 + kt, &sBh[j1*512]);  gl16(wl_p + b1 + kt, &sBl[j1*512]); }
    __syncthreads();
    bf16x8 ah[4], al[4], bh[4], bl[4];
    #pragma unroll
    for (int i=0;i<4;i++) {
      ah[i] = *(const bf16x8*)&sAh[baseA + i*512];
      al[i] = *(const bf16x8*)&sAl[baseA + i*512];
    }
    #pragma unroll
    for (int j=0;j<4;j++) {
      if (wn + 16*j < nvalid) {
        bh[j] = *(const bf16x8*)&sBh[baseB + j*512];
        bl[j] = *(const bf16x8*)&sBl[baseB + j*512];
      }
    }
    #pragma unroll
    for (int i=0;i<4;i++)
      #pragma unroll
      for (int j=0;j<4;j++) {
        if (wn + 16*j < nvalid) {
          f32x4 t = __builtin_amdgcn_mfma_f32_16x16x32_bf16(ah[i], bl[j], acc[i][j], 0,0,0);
          t       = __builtin_amdgcn_mfma_f32_16x16x32_bf16(al[i], bh[j], t,         0,0,0);
          acc[i][j] = __builtin_amdgcn_mfma_f32_16x16x32_bf16(ah[i], bh[j], t,       0,0,0);
        }
      }
  }
  #pragma unroll
  for (int i=0;i<4;i++)
  #pragma unroll
  for (int j=0;j<4;j++)
  #pragma unroll
  for (int r=0;r<4;r++) {
    int mo = m0 + wm + i*16 + quad*4 + r;
    int no = n0 + wn + j*16 + l16;
    if (no < N) C0[((size_t)dir*MR + mo)*DIP + no] = acc[i][j][r];
  }
}

// ------- final GEMM (z=dir, both dirs concurrent): 64x128 tile, 256 thr -------
__global__ __launch_bounds__(256) void gemm_final(
    const u16* __restrict__ zt, const u16* __restrict__ Wch, const u16* __restrict__ Wcl,
    float* __restrict__ out)
{
  constexpr int K = 1024;
  __shared__ __align__(16) u16 sAh[64*32];
  __shared__ __align__(16) u16 sAl[64*32];
  __shared__ __align__(16) u16 sBh[128*32];
  __shared__ __align__(16) u16 sBl[128*32];
  const int tid = threadIdx.x;
  const int dir = blockIdx.z;
  const int m0 = blockIdx.x * 64;
  const int n0 = blockIdx.y * 128;
  const int lane = tid & 63;
  const int wid  = tid >> 6;
  const u16* ah_p = zt + 2048 + (size_t)dir*MR*ZROW;
  const u16* al_p = zt + 3072 + (size_t)dir*MR*ZROW;
  const u16* wh_p = Wch + (size_t)dir*NOUT;
  const u16* wl_p = Wcl + (size_t)dir*NOUT;
  const int cp = lane & 3;
  auto goffA = [&](int j)->size_t {
    int row = 16*j + (lane>>2);
    int s = (row>>1) & 3;
    int kc = (cp ^ s) * 8;
    int grow = m0 + row;
    if (dir) grow = (grow & ~1023) + (1023 - (grow & 1023));  // read flipped row
    return (size_t)grow*ZROW + kc;
  };
  auto goffB = [&](int j)->size_t {
    int row = 16*j + (lane>>2);
    int s = (row>>1) & 3;
    int kc = (cp ^ s) * 8;
    return (size_t)(n0 + row)*1024 + kc;
  };
  const size_t a0 = goffA(wid);
  const size_t b0 = goffB(wid), b1 = goffB(wid+4);
  const int quad = lane >> 4;
  const int l16  = lane & 15;
  const int qx = quad ^ ((l16>>1)&3);
  const int baseA = (l16*4 + qx)*8;
  const int baseB = ((wid*32 + l16)*4 + qx)*8;
  f32x4 acc[4][2] = {};
  for (int kt = 0; kt < K; kt += 32) {
    __syncthreads();
    gl16(ah_p + a0 + kt, &sAh[wid*512]);
    gl16(al_p + a0 + kt, &sAl[wid*512]);
    gl16(wh_p + b0 + kt, &sBh[wid*512]);  gl16(wh_p + b1 + kt, &sBh[(wid+4)*512]);
    gl16(wl_p + b0 + kt, &sBl[wid*512]);  gl16(wl_p + b1 + kt, &sBl[(wid+4)*512]);
    __syncthreads();
    bf16x8 ah[4], al[4], bh[2], bl[2];
    #pragma unroll
    for (int i=0;i<4;i++) {
      ah[i] = *(const bf16x8*)&sAh[baseA + i*512];
      al[i] = *(const bf16x8*)&sAl[baseA + i*512];
    }
    #pragma unroll
    for (int j=0;j<2;j++) {
      bh[j] = *(const bf16x8*)&sBh[baseB + j*512];
      bl[j] = *(const bf16x8*)&sBl[baseB + j*512];
    }
    #pragma unroll
    for (int i=0;i<4;i++)
      #pragma unroll
      for (int j=0;j<2;j++) {
        f32x4 t = __builtin_amdgcn_mfma_f32_16x16x32_bf16(ah[i], bl[j], acc[i][j], 0,0,0);
        t       = __builtin_amdgcn_mfma_f32_16x16x32_bf16(al[i], bh[j], t,         0,0,0);
        acc[i][j] = __builtin_amdgcn_mfma_f32_16x16x32_bf16(ah[i], bh[j], t,       0,0,0);
      }
  }
  #pragma unroll
  for (int i=0;i<4;i++)
  #pragma unroll
  for (int j=0;j<2;j++)
  #pragma unroll
  for (int r=0;r<4;r++) {
    int mo = m0 + i*16 + quad*4 + r;
    int no = n0 + wid*32 + j*16 + l16;
    atomicAdd(&out[(size_t)mo*512 + no], acc[i][j][r]);
  }
}

// ---------------- K3: depthwise conv + SiLU + dt softplus ----------------
// 8 output rows per block: 11-row register window slides across 8 outputs.
__global__ __launch_bounds__(320) void conv_dt(
  const float* __restrict__ Z,
  const float* __restrict__ f_cw, const float* __restrict__ f_cb,
  const float* __restrict__ b_cw, const float* __restrict__ b_cb,
  const float* __restrict__ f_dtb, const float* __restrict__ b_dtb,
  unsigned* __restrict__ xconv,
  unsigned* __restrict__ Bc, unsigned* __restrict__ Cc,
  float* __restrict__ dtq)
{
  int bsw = blockIdx.x;
  int b = (bsw & 7)*128 + (bsw >> 3);   // bijective XCD remap (1024 = 8*128)
  int r0 = b*8;                         // rows r0..r0+7: same dir, same sequence
  int dir = r0 >> 12;
  int t0 = r0 & 1023;
  const float* cw  = dir ? b_cw : f_cw;
  const float* cb  = dir ? b_cb : f_cb;
  const float* dtb = dir ? b_dtb : f_dtb;
  int tid = threadIdx.x;
  if (tid < 288) {
    int c0 = tid*4;
    float4 w0 = *(const float4*)&cw[c0*4];
    float4 w1 = *(const float4*)&cw[(c0+1)*4];
    float4 w2 = *(const float4*)&cw[(c0+2)*4];
    float4 w3 = *(const float4*)&cw[(c0+3)*4];
    float4 cb4 = *(const float4*)&cb[c0];
    const float4 zero4 = {0.f,0.f,0.f,0.f};
    float4 wnd[11];
    #pragma unroll
    for (int j=0;j<11;j++) {
      int a = r0 - 3 + j;
      wnd[j] = (a >= 0) ? *(const float4*)(Z + (size_t)a*DIP + 1024 + c0) : zero4;
    }
    #pragma unroll
    for (int k=0;k<8;k++) {
      int t = t0 + k;
      float4 z0 = (t >= 3) ? wnd[k]   : zero4;
      float4 z1 = (t >= 2) ? wnd[k+1] : zero4;
      float4 z2 = (t >= 1) ? wnd[k+2] : zero4;
      float4 z3 = wnd[k+3];
      float4 a = cb4;
      a.x += z0.x*w0.x + z1.x*w0.y + z2.x*w0.z + z3.x*w0.w;
      a.y += z0.y*w1.x + z1.y*w1.y + z2.y*w1.z + z3.y*w1.w;
      a.z += z0.z*w2.x + z1.z*w2.y + z2.z*w2.z + z3.z*w2.w;
      a.w += z0.w*w3.x + z1.w*w3.y + z2.w*w3.z + z3.w*w3.w;
      float4 v;
      v.x = a.x * sigm(a.x); v.y = a.y * sigm(a.y);
      v.z = a.z * sigm(a.z); v.w = a.w * sigm(a.w);
      uint4 pv;
      pv.x = packbf(v.x); pv.y = packbf(v.y);
      pv.z = packbf(v.z); pv.w = packbf(v.w);
      int bm = r0 + k;
      if (c0 < 1024)      *(uint4*)&xconv[(size_t)bm*DI + c0] = pv;
      else if (c0 < 1088) *(uint4*)&Bc[(size_t)bm*64 + (c0-1024)] = pv;
      else                *(uint4*)&Cc[(size_t)bm*64 + (c0-1088)] = pv;
    }
  }
  if (tid < NH) {
    #pragma unroll
    for (int k=0;k<8;k++) {
      int bm = r0 + k;
      float dtraw = Z[(size_t)bm*DIP + 2176 + tid] + dtb[tid];
      float dt = (dtraw > 20.f) ? dtraw : log1pf(__expf(dtraw));
      dtq[(size_t)bm*NH + tid] = dt;
    }
  }
}

// ---------- K4a: S-only chunk kernel ----------
__global__ __launch_bounds__(256) void scan_mfma(
  const float* __restrict__ dtq, const unsigned* __restrict__ xconv,
  const unsigned* __restrict__ Bc,
  const float* __restrict__ f_Al, const float* __restrict__ b_Al,
  float* __restrict__ cumdec, float* __restrict__ S)
{
  __shared__ float scum[4][32];
  __shared__ float sdt[4][32];
  int bx = blockIdx.x;
  int hq = bx & 3, chunk = (bx>>2)&(NCH-1), dirb = bx>>7;
  int w = threadIdx.x >> 6, lane = threadIdx.x & 63;
  int h = hq*4 + w;
  int base_row = dirb*1024 + chunk*CT;
  const int quad = lane >> 4, l16 = lane & 15;
  const float* Al = (dirb >= 4) ? b_Al : f_Al;
  float A = -__expf(Al[h]);
  float dtl = 0.f, cum = 0.f;
  if (lane < 32) { dtl = dtq[(size_t)(base_row + lane)*16 + h]; cum = dtl; }
  #pragma unroll
  for (int off=1; off<32; off<<=1) {
    int src = (lane >= off) ? lane-off : lane;
    float o = __shfl(cum, src);
    if (lane >= off && lane < 32) cum += o;
  }
  if (lane < 32) {
    sdt[w][lane]  = dtl;
    scum[w][lane] = cum;
    cumdec[(size_t)(base_row + lane)*16 + h] = __expf(A*cum);
  }
  // ---- X^T fragments ----
  bf16x8 xhf[4], xlf[4];
  const unsigned* xp = xconv + (size_t)(base_row + quad*8)*1024 + h*64 + l16;
  #pragma unroll
  for (int jp=0;jp<4;jp++) unpack8s(xp + 16*jp, 1024, xhf[jp], xlf[jp]);
  // ---- S^T = X^T @ (w.B)^T ----
  float wv[8];
  float ct31 = scum[w][31];
  #pragma unroll
  for (int jj=0;jj<8;jj++) {
    int s = quad*8 + jj;
    wv[jj] = sdt[w][s] * __expf(A*(ct31 - scum[w][s]));
  }
  bf16x8 wbh[4], wbl[4];
  #pragma unroll
  for (int j2=0;j2<4;j2++) {
    u16x8 hu, lu; u16 hh, ll;
    #pragma unroll
    for (int jj=0;jj<8;jj++) {
      float b = unpackf(Bc[(size_t)(base_row + quad*8 + jj)*64 + 16*j2 + l16]);
      splitbf(wv[jj]*b, hh, ll); hu[jj]=hh; lu[jj]=ll;
    }
    wbh[j2] = __builtin_bit_cast(bf16x8, hu);
    wbl[j2] = __builtin_bit_cast(bf16x8, lu);
  }
  size_t inst = ((size_t)(dirb*16+h)*NCH + chunk)*4096;
  __builtin_amdgcn_s_setprio(1);
  #pragma unroll
  for (int mp=0;mp<4;mp++)
  #pragma unroll
  for (int j2=0;j2<4;j2++) {
    f32x4 acc = {};
    acc = __builtin_amdgcn_mfma_f32_16x16x32_bf16(xhf[mp], wbl[j2], acc, 0,0,0);
    acc = __builtin_amdgcn_mfma_f32_16x16x32_bf16(xlf[mp], wbh[j2], acc, 0,0,0);
    acc = __builtin_amdgcn_mfma_f32_16x16x32_bf16(xhf[mp], wbh[j2], acc, 0,0,0);
    #pragma unroll
    for (int r=0;r<4;r++)
      S[inst + (size_t)(16*mp + quad*4 + r)*64 + 16*j2 + l16] = acc[r];
  }
  __builtin_amdgcn_s_setprio(0);
}

// ---------- K4b: inter-chunk combine; S[c] overwritten with PACKED h_start(c) ----------
__global__ __launch_bounds__(256) void scan_comb(
  const float* __restrict__ cumdec, float* __restrict__ S)
{
  int ih = blockIdx.x >> 4;            // dirb*16 + h
  int sub = blockIdx.x & 15;
  int dirb = ih >> 4, h = ih & 15;
  int elem = sub*256 + threadIdx.x;    // 0..4095 = p*64+n
  size_t base = (size_t)ih*NCH*4096 + elem;
  float hr = 0.f;
  #pragma unroll
  for (int c=0;c<NCH;c++) {
    float P = cumdec[((size_t)(dirb*1024 + c*CT + CT-1))*16 + h];
    float s = S[base + c*4096];
    S[base + c*4096] = __builtin_bit_cast(float, packbf(hr));  // packed h_start
    hr = fmaf(hr, P, s);
  }
}

// ---------- K4c: fused G/M/Y1 + Y2 + gate + rmsnorm ----------
__global__ __launch_bounds__(1024) void scan_y2_gate(
  const unsigned* __restrict__ Cc, const unsigned* __restrict__ Bc,
  const float* __restrict__ S, const unsigned* __restrict__ xconv,
  const float* Z, u16* zt, const float* __restrict__ dtq,
  const float* __restrict__ f_Al, const float* __restrict__ b_Al,
  const float* __restrict__ f_D, const float* __restrict__ b_D,
  const float* __restrict__ f_gw, const float* __restrict__ b_gw)
{
  __shared__ __align__(16) u16 sMh[16][32*40];
  __shared__ __align__(16) u16 sMl[16][32*40];
  __shared__ float sdt2[16][32];
  __shared__ float scum2[16][32];
  __shared__ float red[32][17];
  __shared__ float rsb[32];
  int bx = blockIdx.x;
  int chunk = bx & (NCH-1), dirb = bx >> 5;
  int w = threadIdx.x >> 6, lane = threadIdx.x & 63;
  int h = w;
  int dir = dirb >> 2;
  int row0 = dirb*1024 + chunk*CT;
  const int quad = lane>>4, l16 = lane&15;
  const float* Alp = (dirb >= 4) ? b_Al : f_Al;
  const float* Dp  = dir ? b_D  : f_D;
  const float* gwp = dir ? b_gw : f_gw;
  float A = -__expf(Alp[h]);
  float Dv = Dp[h];
  // dt + prefix (lanes 0..31) -> per-head LDS
  float dtl = 0.f, cum = 0.f;
  if (lane < 32) { dtl = dtq[(size_t)(row0 + lane)*16 + h]; cum = dtl; }
  #pragma unroll
  for (int off=1; off<32; off<<=1) {
    int src = (lane >= off) ? lane-off : lane;
    float o = __shfl(cum, src);
    if (lane >= off && lane < 32) cum += o;
  }
  if (lane < 32) { sdt2[h][lane] = dtl; scum2[h][lane] = cum; }
  // ---- G = C @ B^T (C frags stay live for Y2) ----
  bf16x8 chf[2][2], clf[2][2];
  f32x4 g[2][2];
  {
    bf16x8 bhf[2][2], blf[2][2];
    #pragma unroll
    for (int i=0;i<2;i++)
    #pragma unroll
    for (int kk=0;kk<2;kk++) {
      unpack8(Cc + (size_t)(row0 + 16*i + l16)*64 + kk*32 + quad*8, chf[i][kk], clf[i][kk]);
      unpack8(Bc + (size_t)(row0 + 16*i + l16)*64 + kk*32 + quad*8, bhf[i][kk], blf[i][kk]);
    }
    __builtin_amdgcn_s_setprio(1);
    #pragma unroll
    for (int i=0;i<2;i++)
    #pragma unroll
    for (int j=0;j<2;j++) {
      f32x4 acc = {};
      #pragma unroll
      for (int kk=0;kk<2;kk++) {
        acc = __builtin_amdgcn_mfma_f32_16x16x32_bf16(chf[i][kk], blf[j][kk], acc, 0,0,0);
        acc = __builtin_amdgcn_mfma_f32_16x16x32_bf16(clf[i][kk], bhf[j][kk], acc, 0,0,0);
        acc = __builtin_amdgcn_mfma_f32_16x16x32_bf16(chf[i][kk], bhf[j][kk], acc, 0,0,0);
      }
      g[i][j] = acc;
    }
    __builtin_amdgcn_s_setprio(0);
  }
  // ---- mask -> M, write split-bf16 to per-head sM ----
  float ctt[2][4];
  #pragma unroll
  for (int i=0;i<2;i++)
  #pragma unroll
  for (int r=0;r<4;r++) ctt[i][r] = scum2[h][16*i + quad*4 + r];
  #pragma unroll
  for (int j=0;j<2;j++) {
    int s = 16*j + l16;
    float cts = scum2[h][s];
    float dts = sdt2[h][s];
    #pragma unroll
    for (int i=0;i<2;i++)
    #pragma unroll
    for (int r=0;r<4;r++) {
      int t = 16*i + quad*4 + r;
      float mv = (s <= t) ? g[i][j][r] * __expf(A*(ctt[i][r]-cts)) * dts : 0.f;
      u16 hh, ll; splitbf(mv, hh, ll);
      sMh[h][t*40 + s] = hh;
      sMl[h][t*40 + s] = ll;
    }
  }
  // at = exp(A*cum) per output row
  float at[2][4];
  #pragma unroll
  for (int i=0;i<2;i++)
  #pragma unroll
  for (int r=0;r<4;r++) at[i][r] = __expf(A*ctt[i][r]);
  // ---- acc = at * (C @ h_start^T)  (chunk>0) ----
  f32x4 acc[2][4] = {};
  if (chunk > 0) {
    size_t inst = ((size_t)(dirb*16+h)*NCH + chunk)*4096;
    const unsigned* Sp = (const unsigned*)S;
    __builtin_amdgcn_s_setprio(1);
    #pragma unroll
    for (int j=0;j<4;j++) {
      bf16x8 hhf[2], hlf[2];
      #pragma unroll
      for (int kk=0;kk<2;kk++)
        unpack8(Sp + inst + (size_t)(16*j + l16)*64 + kk*32 + quad*8, hhf[kk], hlf[kk]);
      #pragma unroll
      for (int i=0;i<2;i++) {
        f32x4 a2 = {};
        #pragma unroll
        for (int kk=0;kk<2;kk++) {
          a2 = __builtin_amdgcn_mfma_f32_16x16x32_bf16(chf[i][kk], hlf[kk], a2, 0,0,0);
          a2 = __builtin_amdgcn_mfma_f32_16x16x32_bf16(clf[i][kk], hhf[kk], a2, 0,0,0);
          a2 = __builtin_amdgcn_mfma_f32_16x16x32_bf16(chf[i][kk], hhf[kk], a2, 0,0,0);
        }
        #pragma unroll
        for (int r=0;r<4;r++) acc[i][j][r] = at[i][r]*a2[r];
      }
    }
    __builtin_amdgcn_s_setprio(0);
  }
  // ---- Y1 = M @ X accumulated on top ----
  {
    bf16x8 xhf[4], xlf[4];
    const unsigned* xp = xconv + (size_t)(row0 + quad*8)*1024 + h*64 + l16;
    #pragma unroll
    for (int jp=0;jp<4;jp++) unpack8s(xp + 16*jp, 1024, xhf[jp], xlf[jp]);
    bf16x8 mhf[2], mlf[2];
    #pragma unroll
    for (int i=0;i<2;i++) {
      mhf[i] = *(const bf16x8*)&sMh[h][(16*i + l16)*40 + quad*8];
      mlf[i] = *(const bf16x8*)&sMl[h][(16*i + l16)*40 + quad*8];
    }
    __builtin_amdgcn_s_setprio(1);
    #pragma unroll
    for (int i=0;i<2;i++)
    #pragma unroll
    for (int jp=0;jp<4;jp++) {
      f32x4 a2 = acc[i][jp];
      a2 = __builtin_amdgcn_mfma_f32_16x16x32_bf16(mhf[i], xlf[jp], a2, 0,0,0);
      a2 = __builtin_amdgcn_mfma_f32_16x16x32_bf16(mlf[i], xhf[jp], a2, 0,0,0);
      a2 = __builtin_amdgcn_mfma_f32_16x16x32_bf16(mhf[i], xhf[jp], a2, 0,0,0);
      acc[i][jp] = a2;
    }
    __builtin_amdgcn_s_setprio(0);
  }
  // ---- gate: v = (y + x*D) * silu(z), v overwrites acc ----
  float pss[2][4] = {};
  #pragma unroll
  for (int i=0;i<2;i++)
  #pragma unroll
  for (int r=0;r<4;r++) {
    int t = 16*i + quad*4 + r;
    size_t gg = (size_t)(row0 + t);
    #pragma unroll
    for (int j=0;j<4;j++) {
      int c = h*64 + 16*j + l16;
      float xv = unpackf(xconv[gg*1024 + c]);
      float zv = Z[gg*DIP + c];
      float v = (acc[i][j][r] + xv*Dv) * (zv * sigm(zv));
      acc[i][j][r] = v;
      pss[i][r] += v*v;
    }
  }
  #pragma unroll
  for (int i=0;i<2;i++)
  #pragma unroll
  for (int r=0;r<4;r++) {
    float s2 = pss[i][r];
    s2 += __shfl_xor(s2, 1, 64);
    s2 += __shfl_xor(s2, 2, 64);
    s2 += __shfl_xor(s2, 4, 64);
    s2 += __shfl_xor(s2, 8, 64);
    if (l16 == 0) red[16*i + quad*4 + r][w] = s2;
  }
  __syncthreads();
  if (threadIdx.x < 32) {
    int t = threadIdx.x;
    float tot = 0.f;
    #pragma unroll
    for (int ww=0; ww<16; ww++) tot += red[t][ww];
    rsb[t] = rsqrtf(tot*(1.f/1024.f) + 1e-5f);
  }
  __syncthreads();
  // normalize + write split planes into Z-tail
  #pragma unroll
  for (int i=0;i<2;i++)
  #pragma unroll
  for (int r=0;r<4;r++) {
    int t = 16*i + quad*4 + r;
    size_t gg = (size_t)(row0 + t);
    float rs = rsb[t];
    #pragma unroll
    for (int j=0;j<4;j++) {
      int c = h*64 + 16*j + l16;
      float o = acc[i][j][r] * rs * gwp[c];
      u16 hh, ll; splitbf(o, hh, ll);
      zt[gg*ZROW + 2048 + c] = hh;
      zt[gg*ZROW + 3072 + c] = ll;
    }
  }
}

extern "C" void kernel_launch(void* const* d_in, const int* in_sizes, int n_in,
                              void* d_out, int out_size, void* d_ws, size_t ws_size,
                              hipStream_t stream)
{
  const float* x        = (const float*)d_in[0];
  const float* norm_w   = (const float*)d_in[1];
  const float* f_in_w   = (const float*)d_in[2];
  const float* f_conv_w = (const float*)d_in[3];
  const float* f_conv_b = (const float*)d_in[4];
  const float* f_dt_bias= (const float*)d_in[5];
  const float* f_A_log  = (const float*)d_in[6];
  const float* f_D      = (const float*)d_in[7];
  const float* f_gw     = (const float*)d_in[8];
  const float* f_out_w  = (const float*)d_in[9];
  const float* b_in_w   = (const float*)d_in[10];
  const float* b_conv_w = (const float*)d_in[11];
  const float* b_conv_b = (const float*)d_in[12];
  const float* b_dt_bias= (const float*)d_in[13];
  const float* b_A_log  = (const float*)d_in[14];
  const float* b_D      = (const float*)d_in[15];
  const float* b_gw     = (const float*)d_in[16];
  const float* b_out_w  = (const float*)d_in[17];
  const float* proj_w   = (const float*)d_in[18];

  char* ws = (char*)d_ws;
  size_t off = 0;
  auto alloc = [&](size_t bytes)->char* {
    char* p = ws + off; off = (off + bytes + 255) & ~(size_t)255; return p;
  };
  u16*   hbh   = (u16*)  alloc((size_t)MR*512*2);
  u16*   hbl   = (u16*)  alloc((size_t)MR*512*2);
  u16*   wH    = (u16*)  alloc(2*(size_t)NIN*2);
  u16*   wL    = (u16*)  alloc(2*(size_t)NIN*2);
  unsigned* wpk = (unsigned*)alloc(3*(size_t)NOUT*4);
  u16*   Wch   = (u16*)  alloc(2*(size_t)NOUT*2);
  u16*   Wcl   = (u16*)  alloc(2*(size_t)NOUT*2);
  float* Z     = (float*)alloc(2*(size_t)MR*DIP*4);
  unsigned* xconv = (unsigned*)alloc(2*(size_t)MR*DI*4);
  unsigned* Bc    = (unsigned*)alloc(2*(size_t)MR*64*4);
  unsigned* Cc    = (unsigned*)alloc(2*(size_t)MR*64*4);
  float* dtq   = (float*)alloc(2*(size_t)MR*NH*4);
  float* cumdec= (float*)alloc(2*(size_t)MR*NH*4);
  float* S     = (float*)alloc((size_t)4096*4096*4);
  u16* wih = wH;  u16* wil = wL;
  // yg planes live in the dead xBC tails of Z rows (see ZROW).

  constexpr int TOT = 2*NIN + 3*NOUT;
  constexpr int WBLK = (TOT + 255)/256;
  prep<<<MR + WBLK + 2048,256,0,stream>>>(x, norm_w, f_in_w, b_in_w,
                                          f_out_w, b_out_w, proj_w,
                                          wH, wL, wpk, hbh, hbl, (float*)d_out);
  gemm_in<<<dim3(32,20,2),256,0,stream>>>(hbh, hbl, wih, wil, Z, wpk, Wch, Wcl);
  conv_dt<<<1024,320,0,stream>>>(Z, f_conv_w, f_conv_b, b_conv_w, b_conv_b,
                                 f_dt_bias, b_dt_bias, xconv, Bc, Cc, dtq);
  scan_mfma<<<1024,256,0,stream>>>(dtq, xconv, Bc, f_A_log, b_A_log, cumdec, S);
  scan_comb<<<2048,256,0,stream>>>(cumdec, S);
  scan_y2_gate<<<256,1024,0,stream>>>(Cc, Bc, S, xconv, Z, (u16*)Z, dtq,
                                      f_A_log, b_A_log, f_D, b_D, f_gw, b_gw);
  gemm_final<<<dim3(64,4,2),256,0,stream>>>((u16*)Z, Wch, Wcl, (float*)d_out);
}